// Round 7
// baseline (3080.066 us; speedup 1.0000x reference)
//
#include <hip/hip_runtime.h>

static constexpr int NN = 1000000;
static constexpr int NE = 16000000;
static constexpr int BSH = 11;                  // 2048-node buckets
static constexpr int BNODES = 1 << BSH;
static constexpr int BMASK = BNODES - 1;
static constexpr int NB = (NN + BMASK) >> BSH;  // 489 buckets
static constexpr int NWG = 512;                 // binning workgroups
static constexpr int EPW = NE / NWG;            // 31250 edges per wg

// ---------- build A: per-(bucket, wg) counts — no atomics to global ----------

__global__ void k_count(const int* __restrict__ col, int* __restrict__ counts) {
    __shared__ int cnt[NB];
    for (int i = threadIdx.x; i < NB; i += blockDim.x) cnt[i] = 0;
    __syncthreads();
    long long e0 = (long long)blockIdx.x * EPW;
    long long e1 = e0 + EPW; if (e1 > NE) e1 = NE;
    long long e = e0 + threadIdx.x;
    for (; e + 768 < e1; e += 1024) {
        int c0 = col[e], c1 = col[e + 256], c2 = col[e + 512], c3 = col[e + 768];
        atomicAdd(&cnt[c0 >> BSH], 1);
        atomicAdd(&cnt[c1 >> BSH], 1);
        atomicAdd(&cnt[c2 >> BSH], 1);
        atomicAdd(&cnt[c3 >> BSH], 1);
    }
    for (; e < e1; e += 256) atomicAdd(&cnt[col[e] >> BSH], 1);
    __syncthreads();
    int w = blockIdx.x;
    for (int i = threadIdx.x; i < NB; i += blockDim.x)
        counts[i * NWG + w] = cnt[i];
}

// ---------- build B1: per-bucket exclusive scan over wgs (in place) ----------

__global__ void k_scan_wg(int* __restrict__ counts, int* __restrict__ bucketTotal) {
    __shared__ int sm[NWG];
    int b = blockIdx.x, t = threadIdx.x;
    int v = counts[b * NWG + t];
    sm[t] = v;
    __syncthreads();
    for (int off = 1; off < NWG; off <<= 1) {
        int x = (t >= off) ? sm[t - off] : 0;
        __syncthreads();
        sm[t] += x;
        __syncthreads();
    }
    counts[b * NWG + t] = sm[t] - v;  // exclusive prefix within bucket
    if (t == NWG - 1) bucketTotal[b] = sm[t];
}

// ---------- build B2: exclusive scan of bucket totals ----------

__global__ void k_scan_total(const int* __restrict__ bucketTotal,
                             int* __restrict__ bucketBase) {
    __shared__ int sm[512];
    int t = threadIdx.x;
    int v = (t < NB) ? bucketTotal[t] : 0;
    sm[t] = v;
    __syncthreads();
    for (int off = 1; off < 512; off <<= 1) {
        int x = (t >= off) ? sm[t - off] : 0;
        __syncthreads();
        sm[t] += x;
        __syncthreads();
    }
    if (t < NB) bucketBase[t] = sm[t] - v;
    if (t == 0) bucketBase[NB] = NE;
}

// ---------- build C: bin edges, single pass over col+row, exact bases --------
// entry = (row << 11) | (col & 2047); row < 2^20 -> 31 bits.

__global__ void k_bin2(const int* __restrict__ row, const int* __restrict__ col,
                       const int* __restrict__ counts, const int* __restrict__ bucketBase,
                       unsigned* __restrict__ binned) {
    __shared__ int off[NB];
    int w = blockIdx.x;
    for (int i = threadIdx.x; i < NB; i += blockDim.x)
        off[i] = bucketBase[i] + counts[i * NWG + w];
    __syncthreads();
    long long e0 = (long long)w * EPW;
    long long e1 = e0 + EPW; if (e1 > NE) e1 = NE;
    long long e = e0 + threadIdx.x;
    for (; e + 768 < e1; e += 1024) {
        int c0 = col[e],       r0 = row[e];
        int c1 = col[e + 256], r1 = row[e + 256];
        int c2 = col[e + 512], r2 = row[e + 512];
        int c3 = col[e + 768], r3 = row[e + 768];
        int p0 = atomicAdd(&off[c0 >> BSH], 1);
        int p1 = atomicAdd(&off[c1 >> BSH], 1);
        int p2 = atomicAdd(&off[c2 >> BSH], 1);
        int p3 = atomicAdd(&off[c3 >> BSH], 1);
        binned[p0] = ((unsigned)r0 << BSH) | (unsigned)(c0 & BMASK);
        binned[p1] = ((unsigned)r1 << BSH) | (unsigned)(c1 & BMASK);
        binned[p2] = ((unsigned)r2 << BSH) | (unsigned)(c2 & BMASK);
        binned[p3] = ((unsigned)r3 << BSH) | (unsigned)(c3 & BMASK);
    }
    for (; e < e1; e += 256) {
        int c = col[e], r = row[e];
        int p = atomicAdd(&off[c >> BSH], 1);
        binned[p] = ((unsigned)r << BSH) | (unsigned)(c & BMASK);
    }
}

// ---------- deg + dis fused: dis[n] = rsqrt(in-degree + 1) ----------

__global__ __launch_bounds__(512) void k_deg_dis(const unsigned* __restrict__ binned,
                                                 const int* __restrict__ bucketBase,
                                                 float* __restrict__ dis) {
    __shared__ int cnt[BNODES];
    int b = blockIdx.x;
    for (int i = threadIdx.x; i < BNODES; i += blockDim.x) cnt[i] = 0;
    __syncthreads();
    int i0 = bucketBase[b], i1 = bucketBase[b + 1];
    int i = i0 + threadIdx.x;
    for (; i + 1536 < i1; i += 2048) {
        unsigned v0 = binned[i],        v1 = binned[i + 512];
        unsigned v2 = binned[i + 1024], v3 = binned[i + 1536];
        atomicAdd(&cnt[v0 & BMASK], 1);
        atomicAdd(&cnt[v1 & BMASK], 1);
        atomicAdd(&cnt[v2 & BMASK], 1);
        atomicAdd(&cnt[v3 & BMASK], 1);
    }
    for (; i < i1; i += 512) atomicAdd(&cnt[binned[i] & BMASK], 1);
    __syncthreads();
    int nodeBase = b << BSH;
    for (int l = threadIdx.x; l < BNODES; l += blockDim.x) {
        int n = nodeBase + l;
        if (n < NN) dis[n] = rsqrtf((float)(cnt[l] + 1));
    }
}

// ---------- layer 1 linear: g1 = (x @ W1) * dis  (stride 16) ----------

__global__ void k_lin1(const float* __restrict__ x, const float* __restrict__ W1,
                       const float* __restrict__ dis, float* __restrict__ g1) {
    __shared__ float w[144];  // 9x16
    if (threadIdx.x < 144) w[threadIdx.x] = W1[threadIdx.x];
    __syncthreads();
    int i = blockIdx.x * blockDim.x + threadIdx.x;
    if (i >= NN) return;
    float xv[9];
#pragma unroll
    for (int k = 0; k < 9; ++k) xv[k] = x[(long long)i * 9 + k];
    float d = dis[i];
#pragma unroll
    for (int j = 0; j < 16; ++j) {
        float acc = 0.f;
#pragma unroll
        for (int k = 0; k < 9; ++k) acc = fmaf(xv[k], w[k * 16 + j], acc);
        g1[(long long)i * 16 + j] = acc * d;
    }
}

// ---------- pull via LDS accumulation: one wg per bucket ----------
// acc[2048][16] = 128 KB LDS. 16 lanes/edge gather g[row] (one 64B line),
// ds_add_f32 into acc[col_local]. Writeout adds self-term and scales by dis.

template <int F, int ASTR>
__global__ __launch_bounds__(512) void k_pull_lds(const unsigned* __restrict__ binned,
                                                  const int* __restrict__ bucketBase,
                                                  const float* __restrict__ dis,
                                                  const float* __restrict__ g,
                                                  float* __restrict__ agg) {
    __shared__ float acc[BNODES][16];  // 128 KB
    int b = blockIdx.x;
    float4* accv = (float4*)&acc[0][0];
    for (int i = threadIdx.x; i < BNODES * 4; i += 512)
        accv[i] = make_float4(0.f, 0.f, 0.f, 0.f);
    __syncthreads();
    int i0 = bucketBase[b], i1 = bucketBase[b + 1];
    int grp = threadIdx.x >> 4;   // 0..31
    int j   = threadIdx.x & 15;
    int e = i0 + grp;
    for (; e + 224 < i1; e += 256) {
        unsigned v0 = binned[e +   0], v1 = binned[e +  32];
        unsigned v2 = binned[e +  64], v3 = binned[e +  96];
        unsigned v4 = binned[e + 128], v5 = binned[e + 160];
        unsigned v6 = binned[e + 192], v7 = binned[e + 224];
        float x0 = g[(long long)(v0 >> BSH) * 16 + j];
        float x1 = g[(long long)(v1 >> BSH) * 16 + j];
        float x2 = g[(long long)(v2 >> BSH) * 16 + j];
        float x3 = g[(long long)(v3 >> BSH) * 16 + j];
        float x4 = g[(long long)(v4 >> BSH) * 16 + j];
        float x5 = g[(long long)(v5 >> BSH) * 16 + j];
        float x6 = g[(long long)(v6 >> BSH) * 16 + j];
        float x7 = g[(long long)(v7 >> BSH) * 16 + j];
        atomicAdd(&acc[v0 & BMASK][j], x0);
        atomicAdd(&acc[v1 & BMASK][j], x1);
        atomicAdd(&acc[v2 & BMASK][j], x2);
        atomicAdd(&acc[v3 & BMASK][j], x3);
        atomicAdd(&acc[v4 & BMASK][j], x4);
        atomicAdd(&acc[v5 & BMASK][j], x5);
        atomicAdd(&acc[v6 & BMASK][j], x6);
        atomicAdd(&acc[v7 & BMASK][j], x7);
    }
    for (; e < i1; e += 32) {
        unsigned v = binned[e];
        atomicAdd(&acc[v & BMASK][j], g[(long long)(v >> BSH) * 16 + j]);
    }
    __syncthreads();
    int nodeBase = b << BSH;
    for (int it = 0; it < BNODES / 32; ++it) {
        int l = it * 32 + grp;
        int n = nodeBase + l;
        if (n < NN && (F == 16 || j < F)) {
            float val = dis[n] * (acc[l][j] + g[(long long)n * 16 + j]);
            agg[(long long)n * ASTR + j] = val;
        }
    }
}

// ---------- layer 2 linear (in-place): g2 = relu(agg1+b1) @ W2 * dis ----------

__global__ void k_lin2(float* __restrict__ agg1g2, const float* __restrict__ b1,
                       const float* __restrict__ W2, const float* __restrict__ dis) {
    __shared__ float w[160];  // 16x10
    __shared__ float bb[16];
    if (threadIdx.x < 160) w[threadIdx.x] = W2[threadIdx.x];
    if (threadIdx.x < 16) bb[threadIdx.x] = b1[threadIdx.x];
    __syncthreads();
    int i = blockIdx.x * blockDim.x + threadIdx.x;
    if (i >= NN) return;
    float hv[16];
#pragma unroll
    for (int k = 0; k < 16; ++k)
        hv[k] = fmaxf(agg1g2[(long long)i * 16 + k] + bb[k], 0.f);
    float d = dis[i];
#pragma unroll
    for (int j = 0; j < 10; ++j) {
        float acc = 0.f;
#pragma unroll
        for (int k = 0; k < 16; ++k) acc = fmaf(hv[k], w[k * 10 + j], acc);
        agg1g2[(long long)i * 16 + j] = acc * d;  // in-place, cols 10..15 stale (finite)
    }
}

// ---------- final: out = (agg2 + b2) @ Wf + bf ----------

__global__ void k_final(const float* __restrict__ agg2, const float* __restrict__ b2,
                        const float* __restrict__ Wf, const float* __restrict__ bf,
                        float* __restrict__ out) {
    __shared__ float w[10];
    __shared__ float bb[10];
    __shared__ float bfv;
    if (threadIdx.x < 10) { w[threadIdx.x] = Wf[threadIdx.x]; bb[threadIdx.x] = b2[threadIdx.x]; }
    if (threadIdx.x == 0) bfv = bf[0];
    __syncthreads();
    int i = blockIdx.x * blockDim.x + threadIdx.x;
    if (i >= NN) return;
    float acc = bfv;
#pragma unroll
    for (int j = 0; j < 10; ++j)
        acc = fmaf(agg2[(long long)i * 10 + j] + bb[j], w[j], acc);
    out[i] = acc;
}

extern "C" void kernel_launch(void* const* d_in, const int* in_sizes, int n_in,
                              void* d_out, int out_size, void* d_ws, size_t ws_size,
                              hipStream_t stream) {
    const float* x  = (const float*)d_in[0];
    const int*   ei = (const int*)d_in[1];
    const float* W1 = (const float*)d_in[2];
    const float* b1 = (const float*)d_in[3];
    const float* W2 = (const float*)d_in[4];
    const float* b2 = (const float*)d_in[5];
    const float* Wf = (const float*)d_in[6];
    const float* bf = (const float*)d_in[7];
    float* out = (float*)d_out;

    const int* row = ei;
    const int* col = ei + NE;

    char* ws = (char*)d_ws;
    size_t off = 0;
    auto alloc = [&](size_t bytes) -> void* {
        void* p = ws + off;
        off += (bytes + 255) & ~255ULL;
        return p;
    };
    int* counts      = (int*)alloc((size_t)NB * NWG * 4);   // 1 MB
    int* bucketTotal = (int*)alloc((size_t)NB * 4);
    int* bucketBase  = (int*)alloc((size_t)(NB + 1) * 4);
    float* dis       = (float*)alloc((size_t)NN * 4);
    unsigned* binned = (unsigned*)alloc((size_t)NE * 4);    // 64 MB, live到 end
    float* g1        = (float*)alloc((size_t)NN * 16 * 4);  // reused as agg2
    float* agg1      = (float*)alloc((size_t)NN * 16 * 4);  // reused in-place as g2

    float* agg2 = g1;  // g1 dead after first pull

    const int TB = 256;
    const int nodeGrid = (NN + TB - 1) / TB;

    k_count<<<NWG, TB, 0, stream>>>(col, counts);
    k_scan_wg<<<NB, NWG, 0, stream>>>(counts, bucketTotal);
    k_scan_total<<<1, 512, 0, stream>>>(bucketTotal, bucketBase);
    k_bin2<<<NWG, TB, 0, stream>>>(row, col, counts, bucketBase, binned);
    k_deg_dis<<<NB, 512, 0, stream>>>(binned, bucketBase, dis);

    k_lin1<<<nodeGrid, TB, 0, stream>>>(x, W1, dis, g1);
    k_pull_lds<16, 16><<<NB, 512, 0, stream>>>(binned, bucketBase, dis, g1, agg1);
    k_lin2<<<nodeGrid, TB, 0, stream>>>(agg1, b1, W2, dis);  // agg1 -> g2 in place
    k_pull_lds<10, 10><<<NB, 512, 0, stream>>>(binned, bucketBase, dis, agg1, agg2);
    k_final<<<nodeGrid, TB, 0, stream>>>(agg2, b2, Wf, bf, out);
}

// Round 8
// 1060.110 us; speedup vs baseline: 2.9054x; 2.9054x over previous
//
#include <hip/hip_runtime.h>

static constexpr int NN = 1000000;
static constexpr int NE = 16000000;
static constexpr int BSH = 11;                  // 2048-node buckets
static constexpr int BNODES = 1 << BSH;
static constexpr int BMASK = BNODES - 1;
static constexpr int NB = (NN + BMASK) >> BSH;  // 489 buckets
static constexpr int NWG = 512;                 // binning workgroups
static constexpr int EPW = NE / NWG;            // 31250 edges per wg

// ---------- build A: per-(bucket, wg) counts — no atomics to global ----------

__global__ void k_count(const int* __restrict__ col, int* __restrict__ counts) {
    __shared__ int cnt[NB];
    for (int i = threadIdx.x; i < NB; i += blockDim.x) cnt[i] = 0;
    __syncthreads();
    long long e0 = (long long)blockIdx.x * EPW;
    long long e1 = e0 + EPW; if (e1 > NE) e1 = NE;
    long long e = e0 + threadIdx.x;
    for (; e + 768 < e1; e += 1024) {
        int c0 = col[e], c1 = col[e + 256], c2 = col[e + 512], c3 = col[e + 768];
        atomicAdd(&cnt[c0 >> BSH], 1);
        atomicAdd(&cnt[c1 >> BSH], 1);
        atomicAdd(&cnt[c2 >> BSH], 1);
        atomicAdd(&cnt[c3 >> BSH], 1);
    }
    for (; e < e1; e += 256) atomicAdd(&cnt[col[e] >> BSH], 1);
    __syncthreads();
    int w = blockIdx.x;
    for (int i = threadIdx.x; i < NB; i += blockDim.x)
        counts[i * NWG + w] = cnt[i];
}

// ---------- build B1: per-bucket exclusive scan over wgs (in place) ----------

__global__ void k_scan_wg(int* __restrict__ counts, int* __restrict__ bucketTotal) {
    __shared__ int sm[NWG];
    int b = blockIdx.x, t = threadIdx.x;
    int v = counts[b * NWG + t];
    sm[t] = v;
    __syncthreads();
    for (int off = 1; off < NWG; off <<= 1) {
        int x = (t >= off) ? sm[t - off] : 0;
        __syncthreads();
        sm[t] += x;
        __syncthreads();
    }
    counts[b * NWG + t] = sm[t] - v;  // exclusive prefix within bucket
    if (t == NWG - 1) bucketTotal[b] = sm[t];
}

// ---------- build B2: exclusive scan of bucket totals; also ptr[NN]=NE ------

__global__ void k_scan_total(const int* __restrict__ bucketTotal,
                             int* __restrict__ bucketBase, int* __restrict__ ptr) {
    __shared__ int sm[512];
    int t = threadIdx.x;
    int v = (t < NB) ? bucketTotal[t] : 0;
    sm[t] = v;
    __syncthreads();
    for (int off = 1; off < 512; off <<= 1) {
        int x = (t >= off) ? sm[t - off] : 0;
        __syncthreads();
        sm[t] += x;
        __syncthreads();
    }
    if (t < NB) bucketBase[t] = sm[t] - v;
    if (t == 0) { bucketBase[NB] = NE; ptr[NN] = NE; }
}

// ---------- build C: bin edges, single pass over col+row, exact bases --------
// entry = (row << 11) | (col & 2047); row < 2^20 -> 31 bits.

__global__ void k_bin2(const int* __restrict__ row, const int* __restrict__ col,
                       const int* __restrict__ counts, const int* __restrict__ bucketBase,
                       unsigned* __restrict__ binned) {
    __shared__ int off[NB];
    int w = blockIdx.x;
    for (int i = threadIdx.x; i < NB; i += blockDim.x)
        off[i] = bucketBase[i] + counts[i * NWG + w];
    __syncthreads();
    long long e0 = (long long)w * EPW;
    long long e1 = e0 + EPW; if (e1 > NE) e1 = NE;
    long long e = e0 + threadIdx.x;
    for (; e + 768 < e1; e += 1024) {
        int c0 = col[e],       r0 = row[e];
        int c1 = col[e + 256], r1 = row[e + 256];
        int c2 = col[e + 512], r2 = row[e + 512];
        int c3 = col[e + 768], r3 = row[e + 768];
        int p0 = atomicAdd(&off[c0 >> BSH], 1);
        int p1 = atomicAdd(&off[c1 >> BSH], 1);
        int p2 = atomicAdd(&off[c2 >> BSH], 1);
        int p3 = atomicAdd(&off[c3 >> BSH], 1);
        binned[p0] = ((unsigned)r0 << BSH) | (unsigned)(c0 & BMASK);
        binned[p1] = ((unsigned)r1 << BSH) | (unsigned)(c1 & BMASK);
        binned[p2] = ((unsigned)r2 << BSH) | (unsigned)(c2 & BMASK);
        binned[p3] = ((unsigned)r3 << BSH) | (unsigned)(c3 & BMASK);
    }
    for (; e < e1; e += 256) {
        int c = col[e], r = row[e];
        int p = atomicAdd(&off[c >> BSH], 1);
        binned[p] = ((unsigned)r << BSH) | (unsigned)(c & BMASK);
    }
}

// ---------- build D: per-bucket histogram + LDS scan -> ptr, dis ----------

__global__ __launch_bounds__(512) void k_ptr_dis(const unsigned* __restrict__ binned,
                                                 const int* __restrict__ bucketBase,
                                                 int* __restrict__ ptr,
                                                 float* __restrict__ dis) {
    __shared__ int cnt[BNODES];
    __shared__ int tsum[512];
    int b = blockIdx.x, t = threadIdx.x;
    for (int i = t; i < BNODES; i += 512) cnt[i] = 0;
    __syncthreads();
    int i0 = bucketBase[b], i1 = bucketBase[b + 1];
    int i = i0 + t;
    for (; i + 1536 < i1; i += 2048) {
        unsigned v0 = binned[i],        v1 = binned[i + 512];
        unsigned v2 = binned[i + 1024], v3 = binned[i + 1536];
        atomicAdd(&cnt[v0 & BMASK], 1);
        atomicAdd(&cnt[v1 & BMASK], 1);
        atomicAdd(&cnt[v2 & BMASK], 1);
        atomicAdd(&cnt[v3 & BMASK], 1);
    }
    for (; i < i1; i += 512) atomicAdd(&cnt[binned[i] & BMASK], 1);
    __syncthreads();
    int s0 = cnt[t * 4], s1 = cnt[t * 4 + 1], s2 = cnt[t * 4 + 2], s3 = cnt[t * 4 + 3];
    int tot = s0 + s1 + s2 + s3;
    tsum[t] = tot;
    __syncthreads();
    for (int off = 1; off < 512; off <<= 1) {
        int x = (t >= off) ? tsum[t - off] : 0;
        __syncthreads();
        tsum[t] += x;
        __syncthreads();
    }
    int base = bucketBase[b] + tsum[t] - tot;  // exclusive
    int n0 = (b << BSH) + t * 4;
    if (n0 < NN)     { ptr[n0]     = base;               dis[n0]     = rsqrtf((float)(s0 + 1)); }
    if (n0 + 1 < NN) { ptr[n0 + 1] = base + s0;          dis[n0 + 1] = rsqrtf((float)(s1 + 1)); }
    if (n0 + 2 < NN) { ptr[n0 + 2] = base + s0 + s1;     dis[n0 + 2] = rsqrtf((float)(s2 + 1)); }
    if (n0 + 3 < NN) { ptr[n0 + 3] = base + s0 + s1 + s2; dis[n0 + 3] = rsqrtf((float)(s3 + 1)); }
}

// ---------- build E: per-bucket scatter (LDS cursors, L2-local writes) ------

__global__ void k_bucket_scatter(const unsigned* __restrict__ binned,
                                 const int* __restrict__ bucketBase,
                                 const int* __restrict__ ptr,
                                 int* __restrict__ sortedRow) {
    __shared__ int cur[BNODES];
    int b = blockIdx.x;
    int nodeBase = b << BSH;
    for (int i = threadIdx.x; i < BNODES; i += blockDim.x) {
        int n = nodeBase + i;
        cur[i] = (n < NN) ? ptr[n] : 0;
    }
    __syncthreads();
    int i0 = bucketBase[b], i1 = bucketBase[b + 1];
    int i = i0 + threadIdx.x;
    for (; i + 768 < i1; i += 1024) {
        unsigned v0 = binned[i],       v1 = binned[i + 256];
        unsigned v2 = binned[i + 512], v3 = binned[i + 768];
        int p0 = atomicAdd(&cur[v0 & BMASK], 1);
        int p1 = atomicAdd(&cur[v1 & BMASK], 1);
        int p2 = atomicAdd(&cur[v2 & BMASK], 1);
        int p3 = atomicAdd(&cur[v3 & BMASK], 1);
        sortedRow[p0] = (int)(v0 >> BSH);
        sortedRow[p1] = (int)(v1 >> BSH);
        sortedRow[p2] = (int)(v2 >> BSH);
        sortedRow[p3] = (int)(v3 >> BSH);
    }
    for (; i < i1; i += 256) {
        unsigned v = binned[i];
        int pos = atomicAdd(&cur[v & BMASK], 1);
        sortedRow[pos] = (int)(v >> BSH);
    }
}

// ---------- layer 1 linear: g1 = (x @ W1) * dis  (stride 16) ----------

__global__ void k_lin1(const float* __restrict__ x, const float* __restrict__ W1,
                       const float* __restrict__ dis, float* __restrict__ g1) {
    __shared__ float w[144];  // 9x16
    if (threadIdx.x < 144) w[threadIdx.x] = W1[threadIdx.x];
    __syncthreads();
    int i = blockIdx.x * blockDim.x + threadIdx.x;
    if (i >= NN) return;
    float xv[9];
#pragma unroll
    for (int k = 0; k < 9; ++k) xv[k] = x[(long long)i * 9 + k];
    float d = dis[i];
#pragma unroll
    for (int j = 0; j < 16; ++j) {
        float acc = 0.f;
#pragma unroll
        for (int k = 0; k < 9; ++k) acc = fmaf(xv[k], w[k * 16 + j], acc);
        g1[(long long)i * 16 + j] = acc * d;
    }
}

// ---------- fused pulls ----------
// 16 lanes/node, register accumulation, 16-deep unrolled gathers (round-6 form).
// MODE 0: writeout fuses layer-2 linear: g2 = (relu(dis*acc + b1) @ W2pad) * dis
//         (W2 zero-padded to 16 output cols -> g2 cols 10..15 are 0)
// MODE 1: writeout fuses final projection: out[n] = sum_j (dis*acc + b2)_j Wf_j + bf

template <int MODE>
__global__ void k_pull_f(const int* __restrict__ ptr, const int* __restrict__ sortedRow,
                         const float* __restrict__ dis, const float* __restrict__ g,
                         const float* __restrict__ p0, const float* __restrict__ p1,
                         const float* __restrict__ p2, float* __restrict__ dst) {
    __shared__ float w2s[256];  // MODE0: W2 padded [16][16]
    __shared__ float c16[16];   // MODE0: b1 | MODE1: b2 padded
    __shared__ float wf16[16];  // MODE1: Wf padded
    __shared__ float bfs;
    if (MODE == 0) {
        if (threadIdx.x < 256) {
            int k = threadIdx.x >> 4, j = threadIdx.x & 15;
            w2s[threadIdx.x] = (j < 10) ? p1[k * 10 + j] : 0.f;  // p1 = W2
        }
        if (threadIdx.x < 16) c16[threadIdx.x] = p0[threadIdx.x];  // p0 = b1 (16)
    } else {
        if (threadIdx.x < 16) {
            c16[threadIdx.x]  = (threadIdx.x < 10) ? p0[threadIdx.x] : 0.f;  // b2
            wf16[threadIdx.x] = (threadIdx.x < 10) ? p1[threadIdx.x] : 0.f;  // Wf
        }
        if (threadIdx.x == 0) bfs = p2[0];
    }
    __syncthreads();

    int grp = threadIdx.x >> 4;
    int j = threadIdx.x & 15;
    int n = blockIdx.x * 16 + grp;
    if (n >= NN) return;
    int e0 = ptr[n], e1 = ptr[n + 1];
    float acc = g[(long long)n * 16 + j];  // self-loop term
    int e = e0;
    for (; e + 16 <= e1; e += 16) {
        int r[16];
#pragma unroll
        for (int k = 0; k < 16; ++k) r[k] = sortedRow[e + k];
        float v[16];
#pragma unroll
        for (int k = 0; k < 16; ++k) v[k] = g[(long long)r[k] * 16 + j];
        float s0 = ((v[0] + v[1]) + (v[2] + v[3])) + ((v[4] + v[5]) + (v[6] + v[7]));
        float s1 = ((v[8] + v[9]) + (v[10] + v[11])) + ((v[12] + v[13]) + (v[14] + v[15]));
        acc += s0 + s1;
    }
    for (; e + 4 <= e1; e += 4) {
        int r0 = sortedRow[e + 0], r1 = sortedRow[e + 1];
        int r2 = sortedRow[e + 2], r3 = sortedRow[e + 3];
        float v0 = g[(long long)r0 * 16 + j];
        float v1 = g[(long long)r1 * 16 + j];
        float v2 = g[(long long)r2 * 16 + j];
        float v3 = g[(long long)r3 * 16 + j];
        acc += (v0 + v1) + (v2 + v3);
    }
    for (; e < e1; ++e)
        acc += g[(long long)sortedRow[e] * 16 + j];

    float d = dis[n];
    float val = d * acc;  // aggregated feature j of node n (post-norm, pre-bias)
    if (MODE == 0) {
        float hv = fmaxf(val + c16[j], 0.f);
        float o = 0.f;
#pragma unroll
        for (int k = 0; k < 16; ++k)
            o = fmaf(__shfl(hv, k, 16), w2s[k * 16 + j], o);
        dst[(long long)n * 16 + j] = o * d;
    } else {
        float t = (val + c16[j]) * wf16[j];
#pragma unroll
        for (int m = 8; m >= 1; m >>= 1) t += __shfl_xor(t, m, 16);
        if (j == 0) dst[n] = t + bfs;
    }
}

extern "C" void kernel_launch(void* const* d_in, const int* in_sizes, int n_in,
                              void* d_out, int out_size, void* d_ws, size_t ws_size,
                              hipStream_t stream) {
    const float* x  = (const float*)d_in[0];
    const int*   ei = (const int*)d_in[1];
    const float* W1 = (const float*)d_in[2];
    const float* b1 = (const float*)d_in[3];
    const float* W2 = (const float*)d_in[4];
    const float* b2 = (const float*)d_in[5];
    const float* Wf = (const float*)d_in[6];
    const float* bf = (const float*)d_in[7];
    float* out = (float*)d_out;

    const int* row = ei;
    const int* col = ei + NE;

    char* ws = (char*)d_ws;
    size_t off = 0;
    auto alloc = [&](size_t bytes) -> void* {
        void* p = ws + off;
        off += (bytes + 255) & ~255ULL;
        return p;
    };
    int* counts      = (int*)alloc((size_t)NB * NWG * 4);   // 1 MB
    int* bucketTotal = (int*)alloc((size_t)NB * 4);
    int* bucketBase  = (int*)alloc((size_t)(NB + 1) * 4);
    int* ptr         = (int*)alloc((size_t)(NN + 1) * 4);
    float* dis       = (float*)alloc((size_t)NN * 4);
    unsigned* binned = (unsigned*)alloc((size_t)NE * 4);    // 64 MB; reused as g2
    int* sortedRow   = (int*)alloc((size_t)NE * 4);         // 64 MB
    float* g1        = (float*)alloc((size_t)NN * 16 * 4);  // 64 MB

    float* g2 = (float*)binned;  // binned dead after k_bucket_scatter

    const int TB = 256;
    const int nodeGrid = (NN + TB - 1) / TB;
    const int pullGrid = (NN + 15) / 16;

    k_count<<<NWG, TB, 0, stream>>>(col, counts);
    k_scan_wg<<<NB, NWG, 0, stream>>>(counts, bucketTotal);
    k_scan_total<<<1, 512, 0, stream>>>(bucketTotal, bucketBase, ptr);
    k_bin2<<<NWG, TB, 0, stream>>>(row, col, counts, bucketBase, binned);
    k_ptr_dis<<<NB, 512, 0, stream>>>(binned, bucketBase, ptr, dis);
    k_bucket_scatter<<<NB, TB, 0, stream>>>(binned, bucketBase, ptr, sortedRow);

    k_lin1<<<nodeGrid, TB, 0, stream>>>(x, W1, dis, g1);
    k_pull_f<0><<<pullGrid, TB, 0, stream>>>(ptr, sortedRow, dis, g1, b1, W2, nullptr, g2);
    k_pull_f<1><<<pullGrid, TB, 0, stream>>>(ptr, sortedRow, dis, g2, b2, Wf, bf, out);
}

// Round 9
// 952.999 us; speedup vs baseline: 3.2320x; 1.1124x over previous
//
#include <hip/hip_runtime.h>

static constexpr int NN = 1000000;
static constexpr int NE = 16000000;
static constexpr int BSH = 11;                  // 2048-node buckets
static constexpr int BNODES = 1 << BSH;
static constexpr int BMASK = BNODES - 1;
static constexpr int NB = (NN + BMASK) >> BSH;  // 489 buckets
static constexpr int NWG = 512;                 // binning workgroups
static constexpr int EPW = NE / NWG;            // 31250 edges per wg
static constexpr int CHUNK = 16;                // flush granularity (64 B)
static constexpr int CAP = 24;                  // staging capacity per bucket
static constexpr int KE = 4;                    // edges per thread per round

// ---------- build A: per-(bucket, wg) counts — no atomics to global ----------

__global__ void k_count(const int* __restrict__ col, int* __restrict__ counts) {
    __shared__ int cnt[NB];
    for (int i = threadIdx.x; i < NB; i += blockDim.x) cnt[i] = 0;
    __syncthreads();
    long long e0 = (long long)blockIdx.x * EPW;
    long long e1 = e0 + EPW; if (e1 > NE) e1 = NE;
    long long e = e0 + threadIdx.x;
    for (; e + 768 < e1; e += 1024) {
        int c0 = col[e], c1 = col[e + 256], c2 = col[e + 512], c3 = col[e + 768];
        atomicAdd(&cnt[c0 >> BSH], 1);
        atomicAdd(&cnt[c1 >> BSH], 1);
        atomicAdd(&cnt[c2 >> BSH], 1);
        atomicAdd(&cnt[c3 >> BSH], 1);
    }
    for (; e < e1; e += 256) atomicAdd(&cnt[col[e] >> BSH], 1);
    __syncthreads();
    int w = blockIdx.x;
    for (int i = threadIdx.x; i < NB; i += blockDim.x)
        counts[i * NWG + w] = cnt[i];
}

// ---------- build B1: per-bucket exclusive scan over wgs (in place) ----------

__global__ void k_scan_wg(int* __restrict__ counts, int* __restrict__ bucketTotal) {
    __shared__ int sm[NWG];
    int b = blockIdx.x, t = threadIdx.x;
    int v = counts[b * NWG + t];
    sm[t] = v;
    __syncthreads();
    for (int off = 1; off < NWG; off <<= 1) {
        int x = (t >= off) ? sm[t - off] : 0;
        __syncthreads();
        sm[t] += x;
        __syncthreads();
    }
    counts[b * NWG + t] = sm[t] - v;  // exclusive prefix within bucket
    if (t == NWG - 1) bucketTotal[b] = sm[t];
}

// ---------- build B2: exclusive scan of bucket totals; also ptr[NN]=NE ------

__global__ void k_scan_total(const int* __restrict__ bucketTotal,
                             int* __restrict__ bucketBase, int* __restrict__ ptr) {
    __shared__ int sm[512];
    int t = threadIdx.x;
    int v = (t < NB) ? bucketTotal[t] : 0;
    sm[t] = v;
    __syncthreads();
    for (int off = 1; off < 512; off <<= 1) {
        int x = (t >= off) ? sm[t - off] : 0;
        __syncthreads();
        sm[t] += x;
        __syncthreads();
    }
    if (t < NB) bucketBase[t] = sm[t] - v;
    if (t == 0) { bucketBase[NB] = NE; ptr[NN] = NE; }
}

// ---------- build C: write-combined binning ----------
// entry = (row << 11) | (col & 2047). Per-bucket LDS staging; complete 16-entry
// chunks are flushed by a single thread as 16 consecutive dword stores so each
// 64B line of `binned` is filled within a tight window (amplification ~1).
// Positions within this wg's reserved span come from LDS cursors; order within
// the span is irrelevant (only bucket-grouping matters downstream).

__global__ __launch_bounds__(256) void k_bin2(const int* __restrict__ row,
                                              const int* __restrict__ col,
                                              const int* __restrict__ counts,
                                              const int* __restrict__ bucketBase,
                                              unsigned* __restrict__ binned) {
    __shared__ unsigned stage[NB][CAP];  // ~47 KB
    __shared__ int scnt[NB];
    __shared__ int gcur[NB];
    int w = blockIdx.x;
    for (int i = threadIdx.x; i < NB; i += 256) {
        scnt[i] = 0;
        gcur[i] = bucketBase[i] + counts[i * NWG + w];
    }
    __syncthreads();
    long long e0 = (long long)w * EPW;
    long long e1 = e0 + EPW; if (e1 > NE) e1 = NE;
    const int TILE = 256 * KE;
    for (long long t0 = e0; t0 < e1; t0 += TILE) {
        int cs[KE], rs[KE];
        bool ok[KE];
#pragma unroll
        for (int k = 0; k < KE; ++k) {
            long long e = t0 + k * 256 + threadIdx.x;
            ok[k] = (e < e1);
            cs[k] = ok[k] ? col[e] : 0;
            rs[k] = ok[k] ? row[e] : 0;
        }
#pragma unroll
        for (int k = 0; k < KE; ++k) {
            if (ok[k]) {
                int b = cs[k] >> BSH;
                unsigned v = ((unsigned)rs[k] << BSH) | (unsigned)(cs[k] & BMASK);
                int s = atomicAdd(&scnt[b], 1);
                if (s < CAP) stage[b][s] = v;
                else { int p = atomicAdd(&gcur[b], 1); binned[p] = v; }  // rare overflow
            }
        }
        __syncthreads();
        for (int b = threadIdx.x; b < NB; b += 256) {
            int n = scnt[b]; if (n > CAP) n = CAP;
            if (n >= CHUNK) {
                int p = atomicAdd(&gcur[b], CHUNK);
#pragma unroll
                for (int q = 0; q < CHUNK; ++q) binned[p + q] = stage[b][q];
                int rem = n - CHUNK;
                for (int q = 0; q < rem; ++q) stage[b][q] = stage[b][CHUNK + q];
                scnt[b] = rem;
            } else {
                scnt[b] = n;
            }
        }
        __syncthreads();
    }
    // tail: flush partial chunks
    for (int b = threadIdx.x; b < NB; b += 256) {
        int n = scnt[b]; if (n > CAP) n = CAP;
        if (n > 0) {
            int p = atomicAdd(&gcur[b], n);
            for (int q = 0; q < n; ++q) binned[p + q] = stage[b][q];
        }
    }
}

// ---------- build D (fused): histogram + scan -> ptr, dis; then scatter ------

__global__ __launch_bounds__(512) void k_sort(const unsigned* __restrict__ binned,
                                              const int* __restrict__ bucketBase,
                                              int* __restrict__ ptr,
                                              float* __restrict__ dis,
                                              int* __restrict__ sortedRow) {
    __shared__ int cnt[BNODES];  // 8 KB: histogram, then cursors
    __shared__ int tsum[512];
    int b = blockIdx.x, t = threadIdx.x;
    for (int i = t; i < BNODES; i += 512) cnt[i] = 0;
    __syncthreads();
    int i0 = bucketBase[b], i1 = bucketBase[b + 1];
    int i = i0 + t;
    for (; i + 1536 < i1; i += 2048) {
        unsigned v0 = binned[i],        v1 = binned[i + 512];
        unsigned v2 = binned[i + 1024], v3 = binned[i + 1536];
        atomicAdd(&cnt[v0 & BMASK], 1);
        atomicAdd(&cnt[v1 & BMASK], 1);
        atomicAdd(&cnt[v2 & BMASK], 1);
        atomicAdd(&cnt[v3 & BMASK], 1);
    }
    for (; i < i1; i += 512) atomicAdd(&cnt[binned[i] & BMASK], 1);
    __syncthreads();
    int s0 = cnt[t * 4], s1 = cnt[t * 4 + 1], s2 = cnt[t * 4 + 2], s3 = cnt[t * 4 + 3];
    int tot = s0 + s1 + s2 + s3;
    tsum[t] = tot;
    __syncthreads();
    for (int off = 1; off < 512; off <<= 1) {
        int x = (t >= off) ? tsum[t - off] : 0;
        __syncthreads();
        tsum[t] += x;
        __syncthreads();
    }
    int base = bucketBase[b] + tsum[t] - tot;  // exclusive start for node t*4
    int n0 = (b << BSH) + t * 4;
    if (n0 < NN)     { ptr[n0]     = base;                dis[n0]     = rsqrtf((float)(s0 + 1)); }
    if (n0 + 1 < NN) { ptr[n0 + 1] = base + s0;           dis[n0 + 1] = rsqrtf((float)(s1 + 1)); }
    if (n0 + 2 < NN) { ptr[n0 + 2] = base + s0 + s1;      dis[n0 + 2] = rsqrtf((float)(s2 + 1)); }
    if (n0 + 3 < NN) { ptr[n0 + 3] = base + s0 + s1 + s2; dis[n0 + 3] = rsqrtf((float)(s3 + 1)); }
    __syncthreads();
    // reuse cnt[] as running cursors
    cnt[t * 4]     = base;
    cnt[t * 4 + 1] = base + s0;
    cnt[t * 4 + 2] = base + s0 + s1;
    cnt[t * 4 + 3] = base + s0 + s1 + s2;
    __syncthreads();
    i = i0 + t;
    for (; i + 1536 < i1; i += 2048) {
        unsigned v0 = binned[i],        v1 = binned[i + 512];
        unsigned v2 = binned[i + 1024], v3 = binned[i + 1536];
        int p0 = atomicAdd(&cnt[v0 & BMASK], 1);
        int p1 = atomicAdd(&cnt[v1 & BMASK], 1);
        int p2 = atomicAdd(&cnt[v2 & BMASK], 1);
        int p3 = atomicAdd(&cnt[v3 & BMASK], 1);
        sortedRow[p0] = (int)(v0 >> BSH);
        sortedRow[p1] = (int)(v1 >> BSH);
        sortedRow[p2] = (int)(v2 >> BSH);
        sortedRow[p3] = (int)(v3 >> BSH);
    }
    for (; i < i1; i += 512) {
        unsigned v = binned[i];
        int pos = atomicAdd(&cnt[v & BMASK], 1);
        sortedRow[pos] = (int)(v >> BSH);
    }
}

// ---------- layer 1 linear: g1 = (x @ W1) * dis  (stride 16) ----------

__global__ void k_lin1(const float* __restrict__ x, const float* __restrict__ W1,
                       const float* __restrict__ dis, float* __restrict__ g1) {
    __shared__ float w[144];  // 9x16
    if (threadIdx.x < 144) w[threadIdx.x] = W1[threadIdx.x];
    __syncthreads();
    int i = blockIdx.x * blockDim.x + threadIdx.x;
    if (i >= NN) return;
    float xv[9];
#pragma unroll
    for (int k = 0; k < 9; ++k) xv[k] = x[(long long)i * 9 + k];
    float d = dis[i];
#pragma unroll
    for (int j = 0; j < 16; ++j) {
        float acc = 0.f;
#pragma unroll
        for (int k = 0; k < 9; ++k) acc = fmaf(xv[k], w[k * 16 + j], acc);
        g1[(long long)i * 16 + j] = acc * d;
    }
}

// ---------- fused pulls (proven round-8 form) ----------
// MODE 0: writeout fuses layer-2 linear: g2 = (relu(dis*acc + b1) @ W2pad) * dis
// MODE 1: writeout fuses final projection: out[n] = sum_j (dis*acc + b2)_j Wf_j + bf

template <int MODE>
__global__ void k_pull_f(const int* __restrict__ ptr, const int* __restrict__ sortedRow,
                         const float* __restrict__ dis, const float* __restrict__ g,
                         const float* __restrict__ p0, const float* __restrict__ p1,
                         const float* __restrict__ p2, float* __restrict__ dst) {
    __shared__ float w2s[256];  // MODE0: W2 padded [16][16]
    __shared__ float c16[16];   // MODE0: b1 | MODE1: b2 padded
    __shared__ float wf16[16];  // MODE1: Wf padded
    __shared__ float bfs;
    if (MODE == 0) {
        if (threadIdx.x < 256) {
            int k = threadIdx.x >> 4, j = threadIdx.x & 15;
            w2s[threadIdx.x] = (j < 10) ? p1[k * 10 + j] : 0.f;  // p1 = W2
        }
        if (threadIdx.x < 16) c16[threadIdx.x] = p0[threadIdx.x];  // p0 = b1 (16)
    } else {
        if (threadIdx.x < 16) {
            c16[threadIdx.x]  = (threadIdx.x < 10) ? p0[threadIdx.x] : 0.f;  // b2
            wf16[threadIdx.x] = (threadIdx.x < 10) ? p1[threadIdx.x] : 0.f;  // Wf
        }
        if (threadIdx.x == 0) bfs = p2[0];
    }
    __syncthreads();

    int grp = threadIdx.x >> 4;
    int j = threadIdx.x & 15;
    int n = blockIdx.x * 16 + grp;
    if (n >= NN) return;
    int e0 = ptr[n], e1 = ptr[n + 1];
    float acc = g[(long long)n * 16 + j];  // self-loop term
    int e = e0;
    for (; e + 16 <= e1; e += 16) {
        int r[16];
#pragma unroll
        for (int k = 0; k < 16; ++k) r[k] = sortedRow[e + k];
        float v[16];
#pragma unroll
        for (int k = 0; k < 16; ++k) v[k] = g[(long long)r[k] * 16 + j];
        float s0 = ((v[0] + v[1]) + (v[2] + v[3])) + ((v[4] + v[5]) + (v[6] + v[7]));
        float s1 = ((v[8] + v[9]) + (v[10] + v[11])) + ((v[12] + v[13]) + (v[14] + v[15]));
        acc += s0 + s1;
    }
    for (; e + 4 <= e1; e += 4) {
        int r0 = sortedRow[e + 0], r1 = sortedRow[e + 1];
        int r2 = sortedRow[e + 2], r3 = sortedRow[e + 3];
        float v0 = g[(long long)r0 * 16 + j];
        float v1 = g[(long long)r1 * 16 + j];
        float v2 = g[(long long)r2 * 16 + j];
        float v3 = g[(long long)r3 * 16 + j];
        acc += (v0 + v1) + (v2 + v3);
    }
    for (; e < e1; ++e)
        acc += g[(long long)sortedRow[e] * 16 + j];

    float d = dis[n];
    float val = d * acc;
    if (MODE == 0) {
        float hv = fmaxf(val + c16[j], 0.f);
        float o = 0.f;
#pragma unroll
        for (int k = 0; k < 16; ++k)
            o = fmaf(__shfl(hv, k, 16), w2s[k * 16 + j], o);
        dst[(long long)n * 16 + j] = o * d;
    } else {
        float t = (val + c16[j]) * wf16[j];
#pragma unroll
        for (int m = 8; m >= 1; m >>= 1) t += __shfl_xor(t, m, 16);
        if (j == 0) dst[n] = t + bfs;
    }
}

extern "C" void kernel_launch(void* const* d_in, const int* in_sizes, int n_in,
                              void* d_out, int out_size, void* d_ws, size_t ws_size,
                              hipStream_t stream) {
    const float* x  = (const float*)d_in[0];
    const int*   ei = (const int*)d_in[1];
    const float* W1 = (const float*)d_in[2];
    const float* b1 = (const float*)d_in[3];
    const float* W2 = (const float*)d_in[4];
    const float* b2 = (const float*)d_in[5];
    const float* Wf = (const float*)d_in[6];
    const float* bf = (const float*)d_in[7];
    float* out = (float*)d_out;

    const int* row = ei;
    const int* col = ei + NE;

    char* ws = (char*)d_ws;
    size_t off = 0;
    auto alloc = [&](size_t bytes) -> void* {
        void* p = ws + off;
        off += (bytes + 255) & ~255ULL;
        return p;
    };
    int* counts      = (int*)alloc((size_t)NB * NWG * 4);   // 1 MB
    int* bucketTotal = (int*)alloc((size_t)NB * 4);
    int* bucketBase  = (int*)alloc((size_t)(NB + 1) * 4);
    int* ptr         = (int*)alloc((size_t)(NN + 1) * 4);
    float* dis       = (float*)alloc((size_t)NN * 4);
    unsigned* binned = (unsigned*)alloc((size_t)NE * 4);    // 64 MB; reused as g2
    int* sortedRow   = (int*)alloc((size_t)NE * 4);         // 64 MB
    float* g1        = (float*)alloc((size_t)NN * 16 * 4);  // 64 MB

    float* g2 = (float*)binned;  // binned dead after k_sort

    const int TB = 256;
    const int nodeGrid = (NN + TB - 1) / TB;
    const int pullGrid = (NN + 15) / 16;

    k_count<<<NWG, TB, 0, stream>>>(col, counts);
    k_scan_wg<<<NB, NWG, 0, stream>>>(counts, bucketTotal);
    k_scan_total<<<1, 512, 0, stream>>>(bucketTotal, bucketBase, ptr);
    k_bin2<<<NWG, TB, 0, stream>>>(row, col, counts, bucketBase, binned);
    k_sort<<<NB, 512, 0, stream>>>(binned, bucketBase, ptr, dis, sortedRow);

    k_lin1<<<nodeGrid, TB, 0, stream>>>(x, W1, dis, g1);
    k_pull_f<0><<<pullGrid, TB, 0, stream>>>(ptr, sortedRow, dis, g1, b1, W2, nullptr, g2);
    k_pull_f<1><<<pullGrid, TB, 0, stream>>>(ptr, sortedRow, dis, g2, b2, Wf, bf, out);
}

// Round 10
// 905.682 us; speedup vs baseline: 3.4008x; 1.0522x over previous
//
#include <hip/hip_runtime.h>

static constexpr int NN = 1000000;
static constexpr int NE = 16000000;
static constexpr int BSH = 11;                  // 2048-node buckets
static constexpr int BNODES = 1 << BSH;
static constexpr int BMASK = BNODES - 1;
static constexpr int NB = (NN + BMASK) >> BSH;  // 489 buckets
static constexpr int NWG = 512;                 // binning workgroups
static constexpr int EPW = NE / NWG;            // 31250 edges per wg
static constexpr int CHUNK = 16;                // flush granularity (64 B)
static constexpr int CAP = 24;                  // staging capacity per bucket
static constexpr int KE = 4;                    // edges per thread per round

// ---------- build A: per-(bucket, wg) counts — 512 thr, 8-deep ----------

__global__ __launch_bounds__(512) void k_count(const int* __restrict__ col,
                                               int* __restrict__ counts) {
    __shared__ int cnt[NB];
    for (int i = threadIdx.x; i < NB; i += 512) cnt[i] = 0;
    __syncthreads();
    long long e0 = (long long)blockIdx.x * EPW;
    long long e1 = e0 + EPW; if (e1 > NE) e1 = NE;
    long long e = e0 + threadIdx.x;
    for (; e + 3584 < e1; e += 4096) {
        int c0 = col[e],        c1 = col[e +  512];
        int c2 = col[e + 1024], c3 = col[e + 1536];
        int c4 = col[e + 2048], c5 = col[e + 2560];
        int c6 = col[e + 3072], c7 = col[e + 3584];
        atomicAdd(&cnt[c0 >> BSH], 1);
        atomicAdd(&cnt[c1 >> BSH], 1);
        atomicAdd(&cnt[c2 >> BSH], 1);
        atomicAdd(&cnt[c3 >> BSH], 1);
        atomicAdd(&cnt[c4 >> BSH], 1);
        atomicAdd(&cnt[c5 >> BSH], 1);
        atomicAdd(&cnt[c6 >> BSH], 1);
        atomicAdd(&cnt[c7 >> BSH], 1);
    }
    for (; e < e1; e += 512) atomicAdd(&cnt[col[e] >> BSH], 1);
    __syncthreads();
    int w = blockIdx.x;
    for (int i = threadIdx.x; i < NB; i += 512)
        counts[i * NWG + w] = cnt[i];
}

// ---------- build B1: per-bucket exclusive scan over wgs (in place) ----------

__global__ void k_scan_wg(int* __restrict__ counts, int* __restrict__ bucketTotal) {
    __shared__ int sm[NWG];
    int b = blockIdx.x, t = threadIdx.x;
    int v = counts[b * NWG + t];
    sm[t] = v;
    __syncthreads();
    for (int off = 1; off < NWG; off <<= 1) {
        int x = (t >= off) ? sm[t - off] : 0;
        __syncthreads();
        sm[t] += x;
        __syncthreads();
    }
    counts[b * NWG + t] = sm[t] - v;  // exclusive prefix within bucket
    if (t == NWG - 1) bucketTotal[b] = sm[t];
}

// ---------- build B2: exclusive scan of bucket totals; also ptr[NN]=NE ------

__global__ void k_scan_total(const int* __restrict__ bucketTotal,
                             int* __restrict__ bucketBase, int* __restrict__ ptr) {
    __shared__ int sm[512];
    int t = threadIdx.x;
    int v = (t < NB) ? bucketTotal[t] : 0;
    sm[t] = v;
    __syncthreads();
    for (int off = 1; off < 512; off <<= 1) {
        int x = (t >= off) ? sm[t - off] : 0;
        __syncthreads();
        sm[t] += x;
        __syncthreads();
    }
    if (t < NB) bucketBase[t] = sm[t] - v;
    if (t == 0) { bucketBase[NB] = NE; ptr[NN] = NE; }
}

// ---------- build C: write-combined binning, 512 thr ----------
// entry = (row << 11) | (col & 2047). Per-bucket LDS staging; complete 16-entry
// chunks flushed as 16 consecutive dword stores (write amplification ~1).

__global__ __launch_bounds__(512) void k_bin2(const int* __restrict__ row,
                                              const int* __restrict__ col,
                                              const int* __restrict__ counts,
                                              const int* __restrict__ bucketBase,
                                              unsigned* __restrict__ binned) {
    __shared__ unsigned stage[NB][CAP];  // ~47 KB
    __shared__ int scnt[NB];
    __shared__ int gcur[NB];
    int w = blockIdx.x;
    for (int i = threadIdx.x; i < NB; i += 512) {
        scnt[i] = 0;
        gcur[i] = bucketBase[i] + counts[i * NWG + w];
    }
    __syncthreads();
    long long e0 = (long long)w * EPW;
    long long e1 = e0 + EPW; if (e1 > NE) e1 = NE;
    const int TILE = 512 * KE;
    for (long long t0 = e0; t0 < e1; t0 += TILE) {
        int cs[KE], rs[KE];
        bool ok[KE];
#pragma unroll
        for (int k = 0; k < KE; ++k) {
            long long e = t0 + k * 512 + threadIdx.x;
            ok[k] = (e < e1);
            cs[k] = ok[k] ? col[e] : 0;
            rs[k] = ok[k] ? row[e] : 0;
        }
#pragma unroll
        for (int k = 0; k < KE; ++k) {
            if (ok[k]) {
                int b = cs[k] >> BSH;
                unsigned v = ((unsigned)rs[k] << BSH) | (unsigned)(cs[k] & BMASK);
                int s = atomicAdd(&scnt[b], 1);
                if (s < CAP) stage[b][s] = v;
                else { int p = atomicAdd(&gcur[b], 1); binned[p] = v; }  // rare overflow
            }
        }
        __syncthreads();
        for (int b = threadIdx.x; b < NB; b += 512) {
            int n = scnt[b]; if (n > CAP) n = CAP;
            if (n >= CHUNK) {
                int p = atomicAdd(&gcur[b], CHUNK);
#pragma unroll
                for (int q = 0; q < CHUNK; ++q) binned[p + q] = stage[b][q];
                int rem = n - CHUNK;
                for (int q = 0; q < rem; ++q) stage[b][q] = stage[b][CHUNK + q];
                scnt[b] = rem;
            } else {
                scnt[b] = n;
            }
        }
        __syncthreads();
    }
    // tail: flush partial chunks
    for (int b = threadIdx.x; b < NB; b += 512) {
        int n = scnt[b]; if (n > CAP) n = CAP;
        if (n > 0) {
            int p = atomicAdd(&gcur[b], n);
            for (int q = 0; q < n; ++q) binned[p + q] = stage[b][q];
        }
    }
}

// ---------- build D (fused): histogram + scan -> ptr, dis; then scatter ------

__global__ __launch_bounds__(512) void k_sort(const unsigned* __restrict__ binned,
                                              const int* __restrict__ bucketBase,
                                              int* __restrict__ ptr,
                                              float* __restrict__ dis,
                                              int* __restrict__ sortedRow) {
    __shared__ int cnt[BNODES];  // 8 KB: histogram, then cursors
    __shared__ int tsum[512];
    int b = blockIdx.x, t = threadIdx.x;
    for (int i = t; i < BNODES; i += 512) cnt[i] = 0;
    __syncthreads();
    int i0 = bucketBase[b], i1 = bucketBase[b + 1];
    int i = i0 + t;
    for (; i + 3584 < i1; i += 4096) {
        unsigned v0 = binned[i],        v1 = binned[i +  512];
        unsigned v2 = binned[i + 1024], v3 = binned[i + 1536];
        unsigned v4 = binned[i + 2048], v5 = binned[i + 2560];
        unsigned v6 = binned[i + 3072], v7 = binned[i + 3584];
        atomicAdd(&cnt[v0 & BMASK], 1);
        atomicAdd(&cnt[v1 & BMASK], 1);
        atomicAdd(&cnt[v2 & BMASK], 1);
        atomicAdd(&cnt[v3 & BMASK], 1);
        atomicAdd(&cnt[v4 & BMASK], 1);
        atomicAdd(&cnt[v5 & BMASK], 1);
        atomicAdd(&cnt[v6 & BMASK], 1);
        atomicAdd(&cnt[v7 & BMASK], 1);
    }
    for (; i < i1; i += 512) atomicAdd(&cnt[binned[i] & BMASK], 1);
    __syncthreads();
    int s0 = cnt[t * 4], s1 = cnt[t * 4 + 1], s2 = cnt[t * 4 + 2], s3 = cnt[t * 4 + 3];
    int tot = s0 + s1 + s2 + s3;
    tsum[t] = tot;
    __syncthreads();
    for (int off = 1; off < 512; off <<= 1) {
        int x = (t >= off) ? tsum[t - off] : 0;
        __syncthreads();
        tsum[t] += x;
        __syncthreads();
    }
    int base = bucketBase[b] + tsum[t] - tot;  // exclusive start for node t*4
    int n0 = (b << BSH) + t * 4;
    if (n0 < NN)     { ptr[n0]     = base;                dis[n0]     = rsqrtf((float)(s0 + 1)); }
    if (n0 + 1 < NN) { ptr[n0 + 1] = base + s0;           dis[n0 + 1] = rsqrtf((float)(s1 + 1)); }
    if (n0 + 2 < NN) { ptr[n0 + 2] = base + s0 + s1;      dis[n0 + 2] = rsqrtf((float)(s2 + 1)); }
    if (n0 + 3 < NN) { ptr[n0 + 3] = base + s0 + s1 + s2; dis[n0 + 3] = rsqrtf((float)(s3 + 1)); }
    __syncthreads();
    // reuse cnt[] as running cursors
    cnt[t * 4]     = base;
    cnt[t * 4 + 1] = base + s0;
    cnt[t * 4 + 2] = base + s0 + s1;
    cnt[t * 4 + 3] = base + s0 + s1 + s2;
    __syncthreads();
    i = i0 + t;
    for (; i + 3584 < i1; i += 4096) {
        unsigned v0 = binned[i],        v1 = binned[i +  512];
        unsigned v2 = binned[i + 1024], v3 = binned[i + 1536];
        unsigned v4 = binned[i + 2048], v5 = binned[i + 2560];
        unsigned v6 = binned[i + 3072], v7 = binned[i + 3584];
        int p0 = atomicAdd(&cnt[v0 & BMASK], 1);
        int p1 = atomicAdd(&cnt[v1 & BMASK], 1);
        int p2 = atomicAdd(&cnt[v2 & BMASK], 1);
        int p3 = atomicAdd(&cnt[v3 & BMASK], 1);
        int p4 = atomicAdd(&cnt[v4 & BMASK], 1);
        int p5 = atomicAdd(&cnt[v5 & BMASK], 1);
        int p6 = atomicAdd(&cnt[v6 & BMASK], 1);
        int p7 = atomicAdd(&cnt[v7 & BMASK], 1);
        sortedRow[p0] = (int)(v0 >> BSH);
        sortedRow[p1] = (int)(v1 >> BSH);
        sortedRow[p2] = (int)(v2 >> BSH);
        sortedRow[p3] = (int)(v3 >> BSH);
        sortedRow[p4] = (int)(v4 >> BSH);
        sortedRow[p5] = (int)(v5 >> BSH);
        sortedRow[p6] = (int)(v6 >> BSH);
        sortedRow[p7] = (int)(v7 >> BSH);
    }
    for (; i < i1; i += 512) {
        unsigned v = binned[i];
        int pos = atomicAdd(&cnt[v & BMASK], 1);
        sortedRow[pos] = (int)(v >> BSH);
    }
}

// ---------- layer 1 linear: g1 = (x @ W1) * dis  (stride 16) ----------

__global__ void k_lin1(const float* __restrict__ x, const float* __restrict__ W1,
                       const float* __restrict__ dis, float* __restrict__ g1) {
    __shared__ float w[144];  // 9x16
    if (threadIdx.x < 144) w[threadIdx.x] = W1[threadIdx.x];
    __syncthreads();
    int i = blockIdx.x * blockDim.x + threadIdx.x;
    if (i >= NN) return;
    float xv[9];
#pragma unroll
    for (int k = 0; k < 9; ++k) xv[k] = x[(long long)i * 9 + k];
    float d = dis[i];
#pragma unroll
    for (int j = 0; j < 16; ++j) {
        float acc = 0.f;
#pragma unroll
        for (int k = 0; k < 9; ++k) acc = fmaf(xv[k], w[k * 16 + j], acc);
        g1[(long long)i * 16 + j] = acc * d;
    }
}

// ---------- fused pulls (proven round-8 form, untouched) ----------
// MODE 0: writeout fuses layer-2 linear: g2 = (relu(dis*acc + b1) @ W2pad) * dis
// MODE 1: writeout fuses final projection: out[n] = sum_j (dis*acc + b2)_j Wf_j + bf

template <int MODE>
__global__ void k_pull_f(const int* __restrict__ ptr, const int* __restrict__ sortedRow,
                         const float* __restrict__ dis, const float* __restrict__ g,
                         const float* __restrict__ p0, const float* __restrict__ p1,
                         const float* __restrict__ p2, float* __restrict__ dst) {
    __shared__ float w2s[256];  // MODE0: W2 padded [16][16]
    __shared__ float c16[16];   // MODE0: b1 | MODE1: b2 padded
    __shared__ float wf16[16];  // MODE1: Wf padded
    __shared__ float bfs;
    if (MODE == 0) {
        if (threadIdx.x < 256) {
            int k = threadIdx.x >> 4, j = threadIdx.x & 15;
            w2s[threadIdx.x] = (j < 10) ? p1[k * 10 + j] : 0.f;  // p1 = W2
        }
        if (threadIdx.x < 16) c16[threadIdx.x] = p0[threadIdx.x];  // p0 = b1 (16)
    } else {
        if (threadIdx.x < 16) {
            c16[threadIdx.x]  = (threadIdx.x < 10) ? p0[threadIdx.x] : 0.f;  // b2
            wf16[threadIdx.x] = (threadIdx.x < 10) ? p1[threadIdx.x] : 0.f;  // Wf
        }
        if (threadIdx.x == 0) bfs = p2[0];
    }
    __syncthreads();

    int grp = threadIdx.x >> 4;
    int j = threadIdx.x & 15;
    int n = blockIdx.x * 16 + grp;
    if (n >= NN) return;
    int e0 = ptr[n], e1 = ptr[n + 1];
    float acc = g[(long long)n * 16 + j];  // self-loop term
    int e = e0;
    for (; e + 16 <= e1; e += 16) {
        int r[16];
#pragma unroll
        for (int k = 0; k < 16; ++k) r[k] = sortedRow[e + k];
        float v[16];
#pragma unroll
        for (int k = 0; k < 16; ++k) v[k] = g[(long long)r[k] * 16 + j];
        float s0 = ((v[0] + v[1]) + (v[2] + v[3])) + ((v[4] + v[5]) + (v[6] + v[7]));
        float s1 = ((v[8] + v[9]) + (v[10] + v[11])) + ((v[12] + v[13]) + (v[14] + v[15]));
        acc += s0 + s1;
    }
    for (; e + 4 <= e1; e += 4) {
        int r0 = sortedRow[e + 0], r1 = sortedRow[e + 1];
        int r2 = sortedRow[e + 2], r3 = sortedRow[e + 3];
        float v0 = g[(long long)r0 * 16 + j];
        float v1 = g[(long long)r1 * 16 + j];
        float v2 = g[(long long)r2 * 16 + j];
        float v3 = g[(long long)r3 * 16 + j];
        acc += (v0 + v1) + (v2 + v3);
    }
    for (; e < e1; ++e)
        acc += g[(long long)sortedRow[e] * 16 + j];

    float d = dis[n];
    float val = d * acc;
    if (MODE == 0) {
        float hv = fmaxf(val + c16[j], 0.f);
        float o = 0.f;
#pragma unroll
        for (int k = 0; k < 16; ++k)
            o = fmaf(__shfl(hv, k, 16), w2s[k * 16 + j], o);
        dst[(long long)n * 16 + j] = o * d;
    } else {
        float t = (val + c16[j]) * wf16[j];
#pragma unroll
        for (int m = 8; m >= 1; m >>= 1) t += __shfl_xor(t, m, 16);
        if (j == 0) dst[n] = t + bfs;
    }
}

extern "C" void kernel_launch(void* const* d_in, const int* in_sizes, int n_in,
                              void* d_out, int out_size, void* d_ws, size_t ws_size,
                              hipStream_t stream) {
    const float* x  = (const float*)d_in[0];
    const int*   ei = (const int*)d_in[1];
    const float* W1 = (const float*)d_in[2];
    const float* b1 = (const float*)d_in[3];
    const float* W2 = (const float*)d_in[4];
    const float* b2 = (const float*)d_in[5];
    const float* Wf = (const float*)d_in[6];
    const float* bf = (const float*)d_in[7];
    float* out = (float*)d_out;

    const int* row = ei;
    const int* col = ei + NE;

    char* ws = (char*)d_ws;
    size_t off = 0;
    auto alloc = [&](size_t bytes) -> void* {
        void* p = ws + off;
        off += (bytes + 255) & ~255ULL;
        return p;
    };
    int* counts      = (int*)alloc((size_t)NB * NWG * 4);   // 1 MB
    int* bucketTotal = (int*)alloc((size_t)NB * 4);
    int* bucketBase  = (int*)alloc((size_t)(NB + 1) * 4);
    int* ptr         = (int*)alloc((size_t)(NN + 1) * 4);
    float* dis       = (float*)alloc((size_t)NN * 4);
    unsigned* binned = (unsigned*)alloc((size_t)NE * 4);    // 64 MB; reused as g2
    int* sortedRow   = (int*)alloc((size_t)NE * 4);         // 64 MB
    float* g1        = (float*)alloc((size_t)NN * 16 * 4);  // 64 MB

    float* g2 = (float*)binned;  // binned dead after k_sort

    const int TB = 256;
    const int nodeGrid = (NN + TB - 1) / TB;
    const int pullGrid = (NN + 15) / 16;

    k_count<<<NWG, 512, 0, stream>>>(col, counts);
    k_scan_wg<<<NB, NWG, 0, stream>>>(counts, bucketTotal);
    k_scan_total<<<1, 512, 0, stream>>>(bucketTotal, bucketBase, ptr);
    k_bin2<<<NWG, 512, 0, stream>>>(row, col, counts, bucketBase, binned);
    k_sort<<<NB, 512, 0, stream>>>(binned, bucketBase, ptr, dis, sortedRow);

    k_lin1<<<nodeGrid, TB, 0, stream>>>(x, W1, dis, g1);
    k_pull_f<0><<<pullGrid, TB, 0, stream>>>(ptr, sortedRow, dis, g1, b1, W2, nullptr, g2);
    k_pull_f<1><<<pullGrid, TB, 0, stream>>>(ptr, sortedRow, dis, g2, b2, Wf, bf, out);
}